// Round 1
// baseline (456.149 us; speedup 1.0000x reference)
//
#include <hip/hip_runtime.h>

// Problem constants (from reference)
constexpr int   NPTS   = 65536;
constexpr int   NVIEWS = 16;
constexpr int   SZ     = 400;          // IMG_SIZE
constexpr int   PAD    = 5;            // PADDING
constexpr int   HP     = 410;          // padded height (SZ + 2*PAD)
constexpr int   WP     = 412;          // padded row width (+2 cols so row stride = 4944 B is 16B-aligned)
constexpr float FOCAL  = 555.555f;
constexpr float SCALE  = 409.0f / 410.0f;  // (Hp-1)/Hp

constexpr long long FEATS_N = (long long)NPTS * NVIEWS * 3 * 25;  // 78,643,200
constexpr int PADIMG_FLOATS = NVIEWS * HP * WP * 3;               // 8,108,160 floats = 32.43 MB
constexpr int ROWB = WP * 3 * 4;                                   // padded row stride bytes = 4944

typedef float vfloat2 __attribute__((ext_vector_type(2)));

// ---------------------------------------------------------------------------
// Setup: per-view combined projection KM = K @ inv(pose @ flip)[:3,:]
// ---------------------------------------------------------------------------
__global__ void setup_km(const float* __restrict__ poses, float* __restrict__ km) {
    int n = threadIdx.x;
    if (n >= NVIEWS) return;
    const float* A = poses + n * 16;  // row-major 4x4
    float x0 = A[0], x1 = A[4], x2 = A[8];
    float y0 = A[1], y1 = A[5], y2 = A[9];
    float z0 = A[2], z1 = A[6], z2 = A[10];
    float t0 = A[3], t1 = A[7], t2 = A[11];

    float M0[4] = { -x0, -x1, -x2,  (x0 * t0 + x1 * t1 + x2 * t2) };
    float M1[4] = {  y0,  y1,  y2, -(y0 * t0 + y1 * t1 + y2 * t2) };
    float M2[4] = {  z0,  z1,  z2, -(z0 * t0 + z1 * t1 + z2 * t2) };

    const float f = FOCAL, cx = 0.5f * SZ;
    float* o = km + n * 12;
#pragma unroll
    for (int k = 0; k < 4; ++k) o[k]     = f * M0[k] + cx * M2[k];
#pragma unroll
    for (int k = 0; k < 4; ++k) o[4 + k] = f * M1[k] + cx * M2[k];
#pragma unroll
    for (int k = 0; k < 4; ++k) o[8 + k] = M2[k];
}

// ---------------------------------------------------------------------------
// Pad kernel: imgpad[n][rr][cc][3] = images[n][rr-5][cc-5][3] (zeros outside).
// Layout (16, 410, 412, 3) f32; the 2 extra columns keep row stride 16B-aligned.
// ---------------------------------------------------------------------------
__global__ __launch_bounds__(256) void pad_kernel(const float* __restrict__ images,
                                                  float* __restrict__ dst) {
    unsigned idx = blockIdx.x * 256u + threadIdx.x;       // padded pixel index
    constexpr unsigned TOT = (unsigned)NVIEWS * HP * WP;  // 2,702,720
    if (idx >= TOT) return;
    unsigned n   = idx / (unsigned)(HP * WP);
    unsigned rem = idx - n * (unsigned)(HP * WP);
    unsigned rr  = rem / (unsigned)WP;
    unsigned cc  = rem - rr * (unsigned)WP;
    float a = 0.0f, b = 0.0f, c = 0.0f;
    int r = (int)rr - PAD, q = (int)cc - PAD;
    if (r >= 0 && r < SZ && q >= 0 && q < SZ) {
        const float* s = images + (((long long)n * SZ + r) * SZ + q) * 3;
        a = s[0]; b = s[1]; c = s[2];
    }
    float* d = dst + (long long)idx * 3;
    d[0] = a; d[1] = b; d[2] = c;
}

// ---------------------------------------------------------------------------
// Cooperative feats kernel.
//   Grid: 131,072 blocks x 256.  view n = (b&7) + 8*((b>>3)&1)  (XCD = b%8:
//   each XCD's gather set = 2 padded views = 4.05 MB ~ L2).
//   Block = 8 point-groups of 32 lanes; group g handles p = (b>>4)*8 + g.
//   Phase 1 (all 32 lanes): project p, derive the 6-row x 96-B bilinear
//   footprint window; 36 aligned dwordx4 chunks staged to LDS (2 loads/lane
//   max).  Footprint proof: r0(i)=floor((x+i)*S), S<1 => r0(i)-r0(0) in [0,4],
//   +1 => 6 rows; cols identical; u,v clamped => rows/cols in [2,407].
//   Phase 2 (lanes 0..24): lane = ij; 4 corners read from LDS (6 contiguous
//   floats per row at one computed address), bilinear, nt-store 3 channels.
// Arithmetic is bit-identical to the previous verified kernel.
// ---------------------------------------------------------------------------
__global__ __launch_bounds__(256) void feats_coop(const float* __restrict__ pts,
                                                  const float* __restrict__ imgpad,
                                                  const float* __restrict__ km,
                                                  float* __restrict__ out) {
    // per point-group: 6 rows * 112 B (96 B data + 16 pad vs bank patterns) = 672 B
    __shared__ float lds[8 * 168];

    unsigned b = blockIdx.x;
    unsigned n = (b & 7u) + 8u * ((b >> 3) & 1u);
    unsigned g = threadIdx.x >> 5;        // point group 0..7
    unsigned l = threadIdx.x & 31u;       // lane within group
    unsigned p = (b >> 4) * 8u + g;

    float px = pts[3 * p], py = pts[3 * p + 1], pz = pts[3 * p + 2];
    const float* k = km + n * 12;
    float psx = k[0] * px + k[1] * py + k[2]  * pz + k[3];
    float psy = k[4] * px + k[5] * py + k[6]  * pz + k[7];
    float psz = k[8] * px + k[9] * py + k[10] * pz + k[11];
    float inv = __builtin_amdgcn_rcpf(psz);
    float u = psx * inv * (1.0f / SZ);
    float v = psy * inv * (1.0f / SZ);
    u = fminf(fmaxf(u, 0.0f), 1.0f);
    v = fminf(fmaxf(v, 0.0f), 1.0f);
    float x = u * SZ + (float)(PAD - 2);  // + PADDING - CROP_STEP
    float y = v * SZ + (float)(PAD - 2);

    // window origin: r_first = floor(r(i=0)) (bit-exact: (x+0.0f)*SCALE == x*SCALE)
    int r_first = (int)floorf(x * SCALE);
    int c_first = (int)floorf(y * SCALE);

    unsigned colb = (unsigned)c_first * 12u;   // byte offset of col c_first in a row
    unsigned base = colb & ~15u;               // 16B-aligned window start within row
    unsigned mis  = colb & 12u;                // 0/4/8/12

    const char* gsrc = (const char*)imgpad
                     + (size_t)n * ((size_t)HP * WP * 3 * 4)
                     + (size_t)((unsigned)r_first * (unsigned)ROWB + base);
    char* lbase = (char*)(lds + g * 168);

    // stage 36 chunks (6 rows x 6 x 16B): lanes 0..31 then lanes 0..3 again
    {
        unsigned q  = l;                       // chunk 0..31
        unsigned row = (q * 43u) >> 8;         // q / 6
        unsigned ch  = q - 6u * row;
        float4 val = *(const float4*)(gsrc + row * (unsigned)ROWB + ch * 16u);
        *(float4*)(lbase + row * 112u + ch * 16u) = val;
    }
    if (l < 4u) {
        unsigned q  = 32u + l;                 // chunks 32..35 (row 5, ch 2..5)
        unsigned row = (q * 43u) >> 8;
        unsigned ch  = q - 6u * row;
        float4 val = *(const float4*)(gsrc + row * (unsigned)ROWB + ch * 16u);
        *(float4*)(lbase + row * 112u + ch * 16u) = val;
    }
    __syncthreads();

    if (l < 25u) {
        unsigned i = (l * 205u) >> 10;   // l / 5  (exact for l < 25)
        unsigned j = l - 5u * i;

        float r  = (x + (float)i) * SCALE;
        float cc = (y + (float)j) * SCALE;
        float r0f = floorf(r);
        float c0f = floorf(cc);
        float wr = r - r0f;
        float wc = cc - c0f;
        unsigned ri = (unsigned)((int)r0f - r_first);  // 0..4
        unsigned cj = (unsigned)((int)c0f - c_first);  // 0..4

        const float* row0 = (const float*)(lbase + ri * 112u + mis + cj * 12u);
        const float* row1 = (const float*)((const char*)row0 + 112);
        float a00 = row0[0], b00 = row0[1], d00 = row0[2];
        float a01 = row0[3], b01 = row0[4], d01 = row0[5];
        float a10 = row1[0], b10 = row1[1], d10 = row1[2];
        float a11 = row1[3], b11 = row1[4], d11 = row1[5];

        float w00 = (1.0f - wr) * (1.0f - wc);
        float w01 = (1.0f - wr) * wc;
        float w10 = wr * (1.0f - wc);
        float w11 = wr * wc;

        float o0 = w00 * a00 + w01 * a01 + w10 * a10 + w11 * a11;
        float o1 = w00 * b00 + w01 * b01 + w10 * b10 + w11 * b11;
        float o2 = w00 * d00 + w01 * d01 + w10 * d10 + w11 * d11;

        unsigned pn = p * 16u + n;
        float* ob = out + (long long)pn * 75 + l;
        __builtin_nontemporal_store(o0, &ob[0]);
        __builtin_nontemporal_store(o1, &ob[25]);
        __builtin_nontemporal_store(o2, &ob[50]);
    }
}

// ---------------------------------------------------------------------------
// FALLBACK path (previous verified kernel) — used if ws too small to pad.
// ---------------------------------------------------------------------------
__device__ __forceinline__ void fetch3(const float* __restrict__ ib, int r, int c,
                                       float& a, float& b, float& d) {
    bool ok = ((unsigned)r < (unsigned)SZ) & ((unsigned)c < (unsigned)SZ);
    int rc = min(max(r, 0), SZ - 1);
    int cc = min(max(c, 0), SZ - 1);
    const float* q = ib + ((long long)rc * SZ + cc) * 3;
    float m = ok ? 1.0f : 0.0f;
    a = q[0] * m;
    b = q[1] * m;
    d = q[2] * m;
}

__global__ __launch_bounds__(256) void feats_kernel(const float* __restrict__ pts,
                                                    const float* __restrict__ imgs,
                                                    const float* __restrict__ km,
                                                    float* __restrict__ out) {
    unsigned b   = blockIdx.x;
    unsigned n   = (b & 7u) + 8u * ((b >> 3) & 1u);
    unsigned idx = (b >> 4) * 256u + threadIdx.x;
    unsigned p   = idx / 25u;
    unsigned ij  = idx % 25u;

    float px = pts[3 * p], py = pts[3 * p + 1], pz = pts[3 * p + 2];
    const float* k = km + n * 12;
    float psx = k[0] * px + k[1] * py + k[2]  * pz + k[3];
    float psy = k[4] * px + k[5] * py + k[6]  * pz + k[7];
    float psz = k[8] * px + k[9] * py + k[10] * pz + k[11];
    float inv = __builtin_amdgcn_rcpf(psz);
    float u = psx * inv * (1.0f / SZ);
    float v = psy * inv * (1.0f / SZ);
    u = fminf(fmaxf(u, 0.0f), 1.0f);
    v = fminf(fmaxf(v, 0.0f), 1.0f);
    float x = u * SZ + (float)(PAD - 2);
    float y = v * SZ + (float)(PAD - 2);

    int i = (int)(ij / 5u);
    int j = (int)(ij % 5u);

    float r  = (x + (float)i) * SCALE;
    float cc = (y + (float)j) * SCALE;
    float r0f = floorf(r);
    float c0f = floorf(cc);
    float wr = r - r0f;
    float wc = cc - c0f;
    int r0 = (int)r0f - PAD;
    int c0 = (int)c0f - PAD;

    const float* ib = imgs + (long long)n * (SZ * SZ * 3);
    float a00, b00, d00, a01, b01, d01, a10, b10, d10, a11, b11, d11;
    fetch3(ib, r0,     c0,     a00, b00, d00);
    fetch3(ib, r0,     c0 + 1, a01, b01, d01);
    fetch3(ib, r0 + 1, c0,     a10, b10, d10);
    fetch3(ib, r0 + 1, c0 + 1, a11, b11, d11);

    float w00 = (1.0f - wr) * (1.0f - wc);
    float w01 = (1.0f - wr) * wc;
    float w10 = wr * (1.0f - wc);
    float w11 = wr * wc;

    float o0 = w00 * a00 + w01 * a01 + w10 * a10 + w11 * a11;
    float o1 = w00 * b00 + w01 * b01 + w10 * b10 + w11 * b11;
    float o2 = w00 * d00 + w01 * d01 + w10 * d10 + w11 * d11;

    unsigned pn = p * 16u + n;
    float* ob = out + (long long)pn * 75 + ij;
    __builtin_nontemporal_store(o0, &ob[0]);
    __builtin_nontemporal_store(o1, &ob[25]);
    __builtin_nontemporal_store(o2, &ob[50]);
}

// ---------------------------------------------------------------------------
// coord_norm kernel: out2[n][p][0..1] = 2*clip(ps.xy/ps.z/SZ,0,1) - 1
// ---------------------------------------------------------------------------
__global__ __launch_bounds__(256) void coord_kernel(const float* __restrict__ pts,
                                                    const float* __restrict__ km,
                                                    float* __restrict__ out2) {
    unsigned tid = blockIdx.x * 256u + threadIdx.x;
    unsigned p = tid & (NPTS - 1);
    unsigned n = tid >> 16;

    float px = pts[3 * p], py = pts[3 * p + 1], pz = pts[3 * p + 2];
    const float* k = km + n * 12;
    float psx = k[0] * px + k[1] * py + k[2]  * pz + k[3];
    float psy = k[4] * px + k[5] * py + k[6]  * pz + k[7];
    float psz = k[8] * px + k[9] * py + k[10] * pz + k[11];
    float inv = __builtin_amdgcn_rcpf(psz);
    float u = psx * inv * (1.0f / SZ);
    float v = psy * inv * (1.0f / SZ);
    u = fminf(fmaxf(u, 0.0f), 1.0f);
    v = fminf(fmaxf(v, 0.0f), 1.0f);

    vfloat2* o = (vfloat2*)out2;
    vfloat2 val = { 2.0f * u - 1.0f, 2.0f * v - 1.0f };
    __builtin_nontemporal_store(val, &o[tid]);
}

extern "C" void kernel_launch(void* const* d_in, const int* in_sizes, int n_in,
                              void* d_out, int out_size, void* d_ws, size_t ws_size,
                              hipStream_t stream) {
    const float* points = (const float*)d_in[0];  // (65536, 3)
    const float* images = (const float*)d_in[1];  // (16, 400, 400, 3)
    const float* poses  = (const float*)d_in[2];  // (16, 4, 4)
    float* out = (float*)d_out;

    const size_t ws_needed = ((size_t)PADIMG_FLOATS + 256) * 4;  // padded imgs + km

    if (ws_size >= ws_needed) {
        float* imgpad = (float*)d_ws;                  // 32.43 MB, 16B-aligned rows
        float* km     = imgpad + PADIMG_FLOATS;

        setup_km<<<1, 64, 0, stream>>>(poses, km);

        constexpr unsigned PADTOT = (unsigned)NVIEWS * HP * WP;   // 2,702,720
        pad_kernel<<<(PADTOT + 255) / 256, 256, 0, stream>>>(images, imgpad);

        // 16 views * 8192 chunks (8 points each) = 131,072 blocks of 256
        feats_coop<<<131072, 256, 0, stream>>>(points, imgpad, km, out);

        coord_kernel<<<4096, 256, 0, stream>>>(points, km, out + FEATS_N);
    } else {
        // fallback: previous verified path (km only in ws)
        float* km = (float*)d_ws;
        setup_km<<<1, 64, 0, stream>>>(poses, km);
        feats_kernel<<<102400, 256, 0, stream>>>(points, images, km, out);
        coord_kernel<<<4096, 256, 0, stream>>>(points, km, out + FEATS_N);
    }
}

// Round 2
// 445.655 us; speedup vs baseline: 1.0235x; 1.0235x over previous
//
#include <hip/hip_runtime.h>

// Problem constants (from reference)
constexpr int   NPTS   = 65536;
constexpr int   NVIEWS = 16;
constexpr int   SZ     = 400;          // IMG_SIZE
constexpr int   PAD    = 5;            // PADDING
constexpr float FOCAL  = 555.555f;
constexpr float SCALE  = 409.0f / 410.0f;  // (Hp-1)/Hp

constexpr long long FEATS_N = (long long)NPTS * NVIEWS * 3 * 25;  // 78,643,200
constexpr int ROWB = SZ * 3 * 4;   // original row stride = 4800 B = 300 * 16 (16B-aligned!)

typedef float vfloat2 __attribute__((ext_vector_type(2)));

// ---------------------------------------------------------------------------
// Setup: per-view combined projection KM = K @ inv(pose @ flip)[:3,:]
// ---------------------------------------------------------------------------
__global__ void setup_km(const float* __restrict__ poses, float* __restrict__ km) {
    int n = threadIdx.x;
    if (n >= NVIEWS) return;
    const float* A = poses + n * 16;  // row-major 4x4
    float x0 = A[0], x1 = A[4], x2 = A[8];
    float y0 = A[1], y1 = A[5], y2 = A[9];
    float z0 = A[2], z1 = A[6], z2 = A[10];
    float t0 = A[3], t1 = A[7], t2 = A[11];

    float M0[4] = { -x0, -x1, -x2,  (x0 * t0 + x1 * t1 + x2 * t2) };
    float M1[4] = {  y0,  y1,  y2, -(y0 * t0 + y1 * t1 + y2 * t2) };
    float M2[4] = {  z0,  z1,  z2, -(z0 * t0 + z1 * t1 + z2 * t2) };

    const float f = FOCAL, cx = 0.5f * SZ;
    float* o = km + n * 12;
#pragma unroll
    for (int k = 0; k < 4; ++k) o[k]     = f * M0[k] + cx * M2[k];
#pragma unroll
    for (int k = 0; k < 4; ++k) o[4 + k] = f * M1[k] + cx * M2[k];
#pragma unroll
    for (int k = 0; k < 4; ++k) o[8 + k] = M2[k];
}

// ---------------------------------------------------------------------------
// Cooperative feats kernel, staging DIRECTLY from the original (unpadded)
// images so the per-XCD gather working set stays L2-resident:
//   view n = (b&7) + 8*((b>>3)&1)  ->  XCD b%8 touches views {n, n+8}:
//   2 x 1.92 MB = 3.84 MB <= 4 MiB L2.   (Round-1's padded copy was
//   2 x 4.95 MB = 9.9 MB -> L2 thrash -> HBM re-reads; that killed the win.)
//
// Block = 8 point-groups of 32 lanes; group g handles p = (b>>4)*8 + g.
// Phase 1: project p; the 25 bilinear taps' corners live in a 6-row x 6-col
//   window of the PADDED image, rows [r_first, r_first+5], cols
//   [c_first, c_first+5]  (padded coords; r_first = floor(x*SCALE)).
//   In ORIGINAL coords that is rows/cols shifted by -PAD, which may hang off
//   the image -> those samples are exactly the zero padding.
//   Key alignment fact: ROWB = 4800 is a multiple of 16, and the staged
//   window starts at a 16B-aligned byte -> every 16B chunk is either fully
//   inside the row [0,4800) or fully in padding. So staging is:
//      chunk valid = (0 <= row_orig < 400) && (0 <= sbyte < 4800)
//      LDS <- valid ? dwordx4(img) : 0
//   36 chunks (6 rows x 6 x 16B) per point, <=2 loads/lane.
// Phase 2 (lanes 0..24): identical bilinear math to the verified kernel;
//   corners read from LDS at  ri*112 + mis + cj*12  (mis = window-start
//   misalignment, same formula as before since window start is col
//   c_first-PAD with colb possibly negative; two's-complement & handles it).
// ---------------------------------------------------------------------------
__global__ __launch_bounds__(256) void feats_coop(const float* __restrict__ pts,
                                                  const float* __restrict__ imgs,
                                                  const float* __restrict__ km,
                                                  float* __restrict__ out) {
    // per point-group: 6 rows * 112 B (96 B data + 16 pad) = 672 B; 8 groups
    __shared__ float lds[8 * 168];

    unsigned b = blockIdx.x;
    unsigned n = (b & 7u) + 8u * ((b >> 3) & 1u);
    unsigned g = threadIdx.x >> 5;        // point group 0..7
    unsigned l = threadIdx.x & 31u;       // lane within group
    unsigned p = (b >> 4) * 8u + g;

    float px = pts[3 * p], py = pts[3 * p + 1], pz = pts[3 * p + 2];
    const float* k = km + n * 12;
    float psx = k[0] * px + k[1] * py + k[2]  * pz + k[3];
    float psy = k[4] * px + k[5] * py + k[6]  * pz + k[7];
    float psz = k[8] * px + k[9] * py + k[10] * pz + k[11];
    float inv = __builtin_amdgcn_rcpf(psz);
    float u = psx * inv * (1.0f / SZ);
    float v = psy * inv * (1.0f / SZ);
    u = fminf(fmaxf(u, 0.0f), 1.0f);
    v = fminf(fmaxf(v, 0.0f), 1.0f);
    float x = u * SZ + (float)(PAD - 2);  // + PADDING - CROP_STEP
    float y = v * SZ + (float)(PAD - 2);

    // window origin (padded coords); bit-exact: (x+0.0f)*SCALE == x*SCALE
    int r_first = (int)floorf(x * SCALE);   // in [2, 402]
    int c_first = (int)floorf(y * SCALE);

    // window start in ORIGINAL image coords: col (c_first - PAD), may be <0
    int colb = (c_first - PAD) * 12;        // byte offset, in [-36, 4824]
    int base = colb & ~15;                  // floor-align 16 (works for neg)
    unsigned mis = (unsigned)(colb & 12);   // 0/4/8/12

    const char* ibase = (const char*)imgs + (size_t)n * (SZ * SZ * 3 * 4);
    char* lbase = (char*)(lds + g * 168);

    // stage 36 chunks (6 rows x 6 x 16B): lanes 0..31 then lanes 0..3 again
    {
        unsigned q   = l;                    // chunk 0..31
        unsigned row = (q * 43u) >> 8;       // q / 6  (exact for q < 36)
        unsigned ch  = q - 6u * row;
        int row_orig = r_first - PAD + (int)row;
        int sbyte    = base + (int)(ch * 16u);
        float4 val = {0.0f, 0.0f, 0.0f, 0.0f};
        if (((unsigned)row_orig < (unsigned)SZ) & ((unsigned)sbyte < (unsigned)ROWB))
            val = *(const float4*)(ibase + (size_t)((unsigned)row_orig * (unsigned)ROWB
                                                    + (unsigned)sbyte));
        *(float4*)(lbase + row * 112u + ch * 16u) = val;
    }
    if (l < 4u) {
        unsigned q   = 32u + l;              // chunks 32..35 (row 5, ch 2..5)
        unsigned row = (q * 43u) >> 8;
        unsigned ch  = q - 6u * row;
        int row_orig = r_first - PAD + (int)row;
        int sbyte    = base + (int)(ch * 16u);
        float4 val = {0.0f, 0.0f, 0.0f, 0.0f};
        if (((unsigned)row_orig < (unsigned)SZ) & ((unsigned)sbyte < (unsigned)ROWB))
            val = *(const float4*)(ibase + (size_t)((unsigned)row_orig * (unsigned)ROWB
                                                    + (unsigned)sbyte));
        *(float4*)(lbase + row * 112u + ch * 16u) = val;
    }
    __syncthreads();

    if (l < 25u) {
        unsigned i = (l * 205u) >> 10;   // l / 5  (exact for l < 25)
        unsigned j = l - 5u * i;

        float r  = (x + (float)i) * SCALE;
        float cc = (y + (float)j) * SCALE;
        float r0f = floorf(r);
        float c0f = floorf(cc);
        float wr = r - r0f;
        float wc = cc - c0f;
        unsigned ri = (unsigned)((int)r0f - r_first);  // 0..4
        unsigned cj = (unsigned)((int)c0f - c_first);  // 0..4

        const float* row0 = (const float*)(lbase + ri * 112u + mis + cj * 12u);
        const float* row1 = (const float*)((const char*)row0 + 112);
        float a00 = row0[0], b00 = row0[1], d00 = row0[2];
        float a01 = row0[3], b01 = row0[4], d01 = row0[5];
        float a10 = row1[0], b10 = row1[1], d10 = row1[2];
        float a11 = row1[3], b11 = row1[4], d11 = row1[5];

        float w00 = (1.0f - wr) * (1.0f - wc);
        float w01 = (1.0f - wr) * wc;
        float w10 = wr * (1.0f - wc);
        float w11 = wr * wc;

        float o0 = w00 * a00 + w01 * a01 + w10 * a10 + w11 * a11;
        float o1 = w00 * b00 + w01 * b01 + w10 * b10 + w11 * b11;
        float o2 = w00 * d00 + w01 * d01 + w10 * d10 + w11 * d11;

        unsigned pn = p * 16u + n;
        float* ob = out + (long long)pn * 75 + l;
        __builtin_nontemporal_store(o0, &ob[0]);
        __builtin_nontemporal_store(o1, &ob[25]);
        __builtin_nontemporal_store(o2, &ob[50]);
    }
}

// ---------------------------------------------------------------------------
// coord_norm kernel: out2[n][p][0..1] = 2*clip(ps.xy/ps.z/SZ,0,1) - 1
// ---------------------------------------------------------------------------
__global__ __launch_bounds__(256) void coord_kernel(const float* __restrict__ pts,
                                                    const float* __restrict__ km,
                                                    float* __restrict__ out2) {
    unsigned tid = blockIdx.x * 256u + threadIdx.x;  // 1,048,576 threads exactly
    unsigned p = tid & (NPTS - 1);
    unsigned n = tid >> 16;

    float px = pts[3 * p], py = pts[3 * p + 1], pz = pts[3 * p + 2];
    const float* k = km + n * 12;
    float psx = k[0] * px + k[1] * py + k[2]  * pz + k[3];
    float psy = k[4] * px + k[5] * py + k[6]  * pz + k[7];
    float psz = k[8] * px + k[9] * py + k[10] * pz + k[11];
    float inv = __builtin_amdgcn_rcpf(psz);
    float u = psx * inv * (1.0f / SZ);
    float v = psy * inv * (1.0f / SZ);
    u = fminf(fmaxf(u, 0.0f), 1.0f);
    v = fminf(fmaxf(v, 0.0f), 1.0f);

    vfloat2* o = (vfloat2*)out2;
    vfloat2 val = { 2.0f * u - 1.0f, 2.0f * v - 1.0f };
    __builtin_nontemporal_store(val, &o[tid]);
}

extern "C" void kernel_launch(void* const* d_in, const int* in_sizes, int n_in,
                              void* d_out, int out_size, void* d_ws, size_t ws_size,
                              hipStream_t stream) {
    const float* points = (const float*)d_in[0];  // (65536, 3)
    const float* images = (const float*)d_in[1];  // (16, 400, 400, 3)
    const float* poses  = (const float*)d_in[2];  // (16, 4, 4)
    float* out = (float*)d_out;
    float* km  = (float*)d_ws;  // 16 * 12 floats

    setup_km<<<1, 64, 0, stream>>>(poses, km);

    // feats: 16 views * 8192 chunks (8 points each) = 131,072 blocks of 256
    feats_coop<<<131072, 256, 0, stream>>>(points, images, km, out);

    // coord_norm: 16*65536 = 1,048,576 threads = 4096 blocks of 256
    coord_kernel<<<4096, 256, 0, stream>>>(points, km, out + FEATS_N);
}

// Round 5
// 429.337 us; speedup vs baseline: 1.0625x; 1.0380x over previous
//
#include <hip/hip_runtime.h>

// Problem constants (from reference)
constexpr int   NPTS   = 65536;
constexpr int   NVIEWS = 16;
constexpr int   SZ     = 400;          // IMG_SIZE
constexpr int   PAD    = 5;            // PADDING
constexpr float FOCAL  = 555.555f;
constexpr float SCALE  = 409.0f / 410.0f;  // (Hp-1)/Hp

constexpr long long FEATS_N = (long long)NPTS * NVIEWS * 3 * 25;  // 78,643,200

typedef float vfloat2 __attribute__((ext_vector_type(2)));
typedef float vfloat4 __attribute__((ext_vector_type(4)));

// ---------------------------------------------------------------------------
// Setup: per-view combined projection KM = K @ inv(pose @ flip)[:3,:]
// ---------------------------------------------------------------------------
__global__ void setup_km(const float* __restrict__ poses, float* __restrict__ km) {
    int n = threadIdx.x;
    if (n >= NVIEWS) return;
    const float* A = poses + n * 16;  // row-major 4x4
    float x0 = A[0], x1 = A[4], x2 = A[8];
    float y0 = A[1], y1 = A[5], y2 = A[9];
    float z0 = A[2], z1 = A[6], z2 = A[10];
    float t0 = A[3], t1 = A[7], t2 = A[11];

    float M0[4] = { -x0, -x1, -x2,  (x0 * t0 + x1 * t1 + x2 * t2) };
    float M1[4] = {  y0,  y1,  y2, -(y0 * t0 + y1 * t1 + y2 * t2) };
    float M2[4] = {  z0,  z1,  z2, -(z0 * t0 + z1 * t1 + z2 * t2) };

    const float f = FOCAL, cx = 0.5f * SZ;
    float* o = km + n * 12;
#pragma unroll
    for (int k = 0; k < 4; ++k) o[k]     = f * M0[k] + cx * M2[k];
#pragma unroll
    for (int k = 0; k < 4; ++k) o[4 + k] = f * M1[k] + cx * M2[k];
#pragma unroll
    for (int k = 0; k < 4; ++k) o[8 + k] = M2[k];
}

// ---------------------------------------------------------------------------
// Gated 3-channel fetch from the (conceptually padded) image — identical
// arithmetic to the round-0 verified kernel.
// ---------------------------------------------------------------------------
__device__ __forceinline__ void fetch3(const float* __restrict__ ib, int r, int c,
                                       float& a, float& b, float& d) {
    bool ok = ((unsigned)r < (unsigned)SZ) & ((unsigned)c < (unsigned)SZ);
    int rc = min(max(r, 0), SZ - 1);
    int cc = min(max(c, 0), SZ - 1);
    const float* q = ib + ((long long)rc * SZ + cc) * 3;
    float m = ok ? 1.0f : 0.0f;
    a = q[0] * m;
    b = q[1] * m;
    d = q[2] * m;
}

// ---------------------------------------------------------------------------
// Dense-store feats kernel ("point-major"):
//   Theory: r0/r2 showed feats time is invariant to gather structure; the
//   invariant cost is the STORE pattern (300 B islands at 4800 B stride per
//   view-partitioned block -> ~25% HBM write efficiency). Fix: one block owns
//   8 points and loops over ALL 16 views, staging each point's full 1200-float
//   output in LDS in global layout, then streaming 38.4 KB of contiguous,
//   16B-aligned nt dwordx4 stores (fill-like write efficiency).
//   Gathers now span all 16 views (31 MB): L2-thrashy but L3-resident; r0/r2
//   proved the gather side has >=100 us of slack.
//
//   Block = 256 threads = 8 groups of 32 lanes; group g owns point
//   p = blockIdx*8 + g; lanes 0..24 = taps (i,j); loop n = 0..15.
//   Per (p,n): project (redundant per lane, cheap), 4x fetch3, bilinear,
//   3 LDS writes at obuf[g][n][c][ij]. Then one sync + coalesced stream-out.
// ---------------------------------------------------------------------------
__global__ __launch_bounds__(256) void feats_dense(const float* __restrict__ pts,
                                                   const float* __restrict__ imgs,
                                                   const float* __restrict__ km,
                                                   float* __restrict__ out) {
    __attribute__((aligned(16))) __shared__ float obuf[8 * 1200];  // 38,400 B

    unsigned b = blockIdx.x;              // 8192 blocks
    unsigned g = threadIdx.x >> 5;        // point group 0..7
    unsigned l = threadIdx.x & 31u;       // lane within group
    unsigned p = b * 8u + g;

    float px = pts[3 * p], py = pts[3 * p + 1], pz = pts[3 * p + 2];

    unsigned i = (l * 205u) >> 10;        // l / 5 (exact for l < 25)
    unsigned j = l - 5u * i;
    bool active = (l < 25u);
    float fi = (float)i, fj = (float)j;

    float* oisl = obuf + g * 1200u;

    for (unsigned n = 0; n < (unsigned)NVIEWS; ++n) {
        const float* k = km + n * 12u;
        float psx = k[0] * px + k[1] * py + k[2]  * pz + k[3];
        float psy = k[4] * px + k[5] * py + k[6]  * pz + k[7];
        float psz = k[8] * px + k[9] * py + k[10] * pz + k[11];
        float inv = __builtin_amdgcn_rcpf(psz);
        float u = psx * inv * (1.0f / SZ);
        float v = psy * inv * (1.0f / SZ);
        u = fminf(fmaxf(u, 0.0f), 1.0f);
        v = fminf(fmaxf(v, 0.0f), 1.0f);
        float x = u * SZ + (float)(PAD - 2);  // + PADDING - CROP_STEP
        float y = v * SZ + (float)(PAD - 2);

        if (active) {
            float r  = (x + fi) * SCALE;
            float cc = (y + fj) * SCALE;
            float r0f = floorf(r);
            float c0f = floorf(cc);
            float wr = r - r0f;
            float wc = cc - c0f;
            int r0 = (int)r0f - PAD;   // original-image row of corner 00
            int c0 = (int)c0f - PAD;

            const float* ib = imgs + (long long)n * (SZ * SZ * 3);
            float a00, b00, d00, a01, b01, d01, a10, b10, d10, a11, b11, d11;
            fetch3(ib, r0,     c0,     a00, b00, d00);
            fetch3(ib, r0,     c0 + 1, a01, b01, d01);
            fetch3(ib, r0 + 1, c0,     a10, b10, d10);
            fetch3(ib, r0 + 1, c0 + 1, a11, b11, d11);

            float w00 = (1.0f - wr) * (1.0f - wc);
            float w01 = (1.0f - wr) * wc;
            float w10 = wr * (1.0f - wc);
            float w11 = wr * wc;

            float o0 = w00 * a00 + w01 * a01 + w10 * a10 + w11 * a11;
            float o1 = w00 * b00 + w01 * b01 + w10 * b10 + w11 * b11;
            float o2 = w00 * d00 + w01 * d01 + w10 * d10 + w11 * d11;

            unsigned base = n * 75u + l;
            oisl[base]       = o0;
            oisl[base + 25u] = o1;
            oisl[base + 50u] = o2;
        }
    }
    __syncthreads();

    // Stream 9600 floats (= 2400 float4) contiguously; block span = 38,400 B,
    // base byte offset b*38400 is 16B-aligned. 2400 = 9*256 + 96.
    const vfloat4* src = (const vfloat4*)obuf;
    vfloat4* dst = (vfloat4*)(out + (size_t)b * 9600u);
    unsigned t = threadIdx.x;
    for (unsigned q = t; q < 2400u; q += 256u)
        __builtin_nontemporal_store(src[q], &dst[q]);
}

// ---------------------------------------------------------------------------
// coord_norm kernel: out2[n][p][0..1] = 2*clip(ps.xy/ps.z/SZ,0,1) - 1
// ---------------------------------------------------------------------------
__global__ __launch_bounds__(256) void coord_kernel(const float* __restrict__ pts,
                                                    const float* __restrict__ km,
                                                    float* __restrict__ out2) {
    unsigned tid = blockIdx.x * 256u + threadIdx.x;  // 1,048,576 threads exactly
    unsigned p = tid & (NPTS - 1);
    unsigned n = tid >> 16;

    float px = pts[3 * p], py = pts[3 * p + 1], pz = pts[3 * p + 2];
    const float* k = km + n * 12;
    float psx = k[0] * px + k[1] * py + k[2]  * pz + k[3];
    float psy = k[4] * px + k[5] * py + k[6]  * pz + k[7];
    float psz = k[8] * px + k[9] * py + k[10] * pz + k[11];
    float inv = __builtin_amdgcn_rcpf(psz);
    float u = psx * inv * (1.0f / SZ);
    float v = psy * inv * (1.0f / SZ);
    u = fminf(fmaxf(u, 0.0f), 1.0f);
    v = fminf(fmaxf(v, 0.0f), 1.0f);

    vfloat2* o = (vfloat2*)out2;
    vfloat2 val = { 2.0f * u - 1.0f, 2.0f * v - 1.0f };
    __builtin_nontemporal_store(val, &o[tid]);
}

extern "C" void kernel_launch(void* const* d_in, const int* in_sizes, int n_in,
                              void* d_out, int out_size, void* d_ws, size_t ws_size,
                              hipStream_t stream) {
    const float* points = (const float*)d_in[0];  // (65536, 3)
    const float* images = (const float*)d_in[1];  // (16, 400, 400, 3)
    const float* poses  = (const float*)d_in[2];  // (16, 4, 4)
    float* out = (float*)d_out;
    float* km  = (float*)d_ws;  // 16 * 12 floats

    setup_km<<<1, 64, 0, stream>>>(poses, km);

    // feats: 65536/8 = 8192 blocks of 256 (8 points each, all 16 views)
    feats_dense<<<8192, 256, 0, stream>>>(points, images, km, out);

    // coord_norm: 16*65536 = 1,048,576 threads = 4096 blocks of 256
    coord_kernel<<<4096, 256, 0, stream>>>(points, km, out + FEATS_N);
}